// Round 2
// baseline (1322.311 us; speedup 1.0000x reference)
//
#include <hip/hip_runtime.h>
#include <stdint.h>

// N=8192 samples, D=4096 statevector dim (fixed by reference)
#define NN 8192
#define DD 4096
#define BM 128          // tile rows (A)
#define BN 256          // tile cols (B)
#define BK 32           // K-step
#define NT (DD / BK)    // 128 K-steps
#define LDS_A 8192      // 128 rows x 32 bf16 = 8 KB  (one of Are/Aim)
#define LDS_B 16384     // 256 rows x 32 bf16 = 16 KB (one of Bre/Bim)
#define LDSBUF 49152    // Are+Aim+Bre+Bim = 48 KB per K-step buffer
#define NTILE 1056      // staircase tiles: sum_{bj=0}^{31} min(64, 2bj+2)

typedef short bf16x8 __attribute__((ext_vector_type(8)));
typedef float f32x4  __attribute__((ext_vector_type(4)));
typedef uint16_t u16x4 __attribute__((ext_vector_type(4)));

// async global->LDS, 16B per lane; LDS dest is linear (wave-uniform base + lane*16)
#define GLOAD(g, l) __builtin_amdgcn_global_load_lds( \
    (__attribute__((address_space(1))) uint32_t*)(void*)(size_t)(g), \
    (__attribute__((address_space(3))) uint32_t*)(void*)(l), 16, 0, 0)

#define VMW12() asm volatile("s_waitcnt vmcnt(12)" ::: "memory")
#define VMW6()  asm volatile("s_waitcnt vmcnt(6)"  ::: "memory")
#define VMW0()  asm volatile("s_waitcnt vmcnt(0)"  ::: "memory")

__device__ __forceinline__ uint16_t f2bf(float x) {
  uint32_t u = __builtin_bit_cast(uint32_t, x);
  return (uint16_t)((u + 0x7fffu + ((u >> 16) & 1u)) >> 16);
}

__global__ void convert_kernel(const float* __restrict__ re, const float* __restrict__ im,
                               uint16_t* __restrict__ reb, uint16_t* __restrict__ imb) {
  size_t i = (size_t)blockIdx.x * blockDim.x + threadIdx.x;
  const size_t stride = (size_t)gridDim.x * blockDim.x;
  const size_t total = (size_t)NN * DD / 4;
  for (; i < total; i += stride) {
    float4 r = ((const float4*)re)[i];
    float4 m = ((const float4*)im)[i];
    u16x4 rb = { f2bf(r.x), f2bf(r.y), f2bf(r.z), f2bf(r.w) };
    u16x4 mb = { f2bf(m.x), f2bf(m.y), f2bf(m.z), f2bf(m.w) };
    ((u16x4*)reb)[i] = rb;
    ((u16x4*)imb)[i] = mb;
  }
}

// One block: 128x256 tile of G for block-pair (bi, bj), bi <= 2bj+1 (staircase covers
// upper triangle; entirely-upper tiles additionally mirror fid^T and zero wts mirror).
// Triple-buffered LDS, prefetch depth 2, counted vmcnt (T3+T4), XOR-swizzled LDS (T2),
// setprio around MFMA clusters (T5).
__global__ __launch_bounds__(512, 2) void gram_kernel(
    const uint16_t* __restrict__ reb, const uint16_t* __restrict__ imb,
    float* __restrict__ wts, float* __restrict__ fidp) {
  __shared__ alignas(16) char lds[3 * LDSBUF];  // 144 KB

  // XCD-aware swizzle (1056 = 8*132, exactly divisible -> bijective)
  const int b = blockIdx.x;
  int t = (b & 7) * 132 + (b >> 3);

  // staircase map: for bj in 0..31, cnt = min(64, 2bj+2) tiles bi = 0..cnt-1
  int bi = 0, bj = 0;
  {
    int acc = 0;
    for (int j = 0; j < 32; ++j) {
      int cnt = 2 * j + 2; if (cnt > 64) cnt = 64;
      if (t < acc + cnt) { bj = j; bi = t - acc; break; }
      acc += cnt;
    }
  }
  const int brow = bi * BM, bcol = bj * BN;

  const int tid = threadIdx.x;
  const int lane = tid & 63;
  const int wid = tid >> 6;          // 8 waves
  const int wr = wid >> 2, wc = wid & 3;  // 2x4 wave grid, 64x64 out per wave
  const int t16 = tid * 16;

  // ---- staging source pointers (pre-swizzled global columns, rule #21) ----
  // thread tid owns chunk (row = tid>>2, kg_phys = tid&3) of each 128-row half-tile;
  // physical LDS slot kg_phys holds logical K-chunk kg_phys ^ (row&3).
  const int srow = tid >> 2;
  const int csw = ((tid & 3) ^ (srow & 3)) * 8;  // element offset of logical chunk
  const uint16_t* sp0 = reb + (size_t)(brow + srow) * DD + csw;        // Are
  const uint16_t* sp1 = imb + (size_t)(brow + srow) * DD + csw;        // Aim
  const uint16_t* sp2 = reb + (size_t)(bcol + srow) * DD + csw;        // Bre lo
  const uint16_t* sp3 = reb + (size_t)(bcol + 128 + srow) * DD + csw;  // Bre hi
  const uint16_t* sp4 = imb + (size_t)(bcol + srow) * DD + csw;        // Bim lo
  const uint16_t* sp5 = imb + (size_t)(bcol + 128 + srow) * DD + csw;  // Bim hi

#define STAGE(s, bf) do {                                   \
    const size_t ko = (size_t)(s) * BK;                     \
    char* lb_ = lds + (bf) * LDSBUF + t16;                  \
    GLOAD(sp0 + ko, lb_);                                   \
    GLOAD(sp1 + ko, lb_ + LDS_A);                           \
    GLOAD(sp2 + ko, lb_ + 2 * LDS_A);                       \
    GLOAD(sp3 + ko, lb_ + 2 * LDS_A + 8192);                \
    GLOAD(sp4 + ko, lb_ + 2 * LDS_A + LDS_B);               \
    GLOAD(sp5 + ko, lb_ + 2 * LDS_A + LDS_B + 8192);        \
  } while (0)

  // ---- fragment read offsets (swizzled: kg ^= row&3 = fr&3, per-lane constant) ----
  const int fr = lane & 15;
  const int kg = lane >> 4;
  const int ksw = ((kg ^ (fr & 3)) << 4);
  const int aoffb = (wr * 64 + fr) * 64 + ksw;  // + m*1024 (Are@0, Aim@8192)
  const int boffb = (wc * 64 + fr) * 64 + ksw;  // + n*1024 (Bre@16384, Bim@32768)

  f32x4 acc_re[4][4], acc_im[4][4];
  const f32x4 z4 = {0.f, 0.f, 0.f, 0.f};
#pragma unroll
  for (int m = 0; m < 4; ++m)
#pragma unroll
    for (int n = 0; n < 4; ++n) { acc_re[m][n] = z4; acc_im[m][n] = z4; }

#define COMPUTE(lbp) do {                                                            \
    const char* lb = (lbp);                                                          \
    bf16x8 ar[4], ai[4], arn[4], br[4], bim[4];                                      \
    _Pragma("unroll") for (int m = 0; m < 4; ++m) {                                  \
      ar[m]  = *(const bf16x8*)(lb + aoffb + m * 1024);                              \
      ai[m]  = *(const bf16x8*)(lb + LDS_A + aoffb + m * 1024);                      \
      arn[m] = ar[m] ^ (short)0x8000;                                                \
    }                                                                                \
    _Pragma("unroll") for (int n = 0; n < 2; ++n) {                                  \
      br[n]  = *(const bf16x8*)(lb + 16384 + boffb + n * 1024);                      \
      bim[n] = *(const bf16x8*)(lb + 32768 + boffb + n * 1024);                      \
    }                                                                                \
    __builtin_amdgcn_s_setprio(1);                                                   \
    _Pragma("unroll") for (int n = 0; n < 2; ++n)                                    \
    _Pragma("unroll") for (int m = 0; m < 4; ++m) {                                  \
      acc_re[m][n] = __builtin_amdgcn_mfma_f32_16x16x32_bf16(ar[m],  br[n],  acc_re[m][n], 0, 0, 0); \
      acc_re[m][n] = __builtin_amdgcn_mfma_f32_16x16x32_bf16(ai[m],  bim[n], acc_re[m][n], 0, 0, 0); \
      acc_im[m][n] = __builtin_amdgcn_mfma_f32_16x16x32_bf16(ai[m],  br[n],  acc_im[m][n], 0, 0, 0); \
      acc_im[m][n] = __builtin_amdgcn_mfma_f32_16x16x32_bf16(arn[m], bim[n], acc_im[m][n], 0, 0, 0); \
    }                                                                                \
    __builtin_amdgcn_s_setprio(0);                                                   \
    _Pragma("unroll") for (int n = 2; n < 4; ++n) {                                  \
      br[n]  = *(const bf16x8*)(lb + 16384 + boffb + n * 1024);                      \
      bim[n] = *(const bf16x8*)(lb + 32768 + boffb + n * 1024);                      \
    }                                                                                \
    __builtin_amdgcn_s_setprio(1);                                                   \
    _Pragma("unroll") for (int n = 2; n < 4; ++n)                                    \
    _Pragma("unroll") for (int m = 0; m < 4; ++m) {                                  \
      acc_re[m][n] = __builtin_amdgcn_mfma_f32_16x16x32_bf16(ar[m],  br[n],  acc_re[m][n], 0, 0, 0); \
      acc_re[m][n] = __builtin_amdgcn_mfma_f32_16x16x32_bf16(ai[m],  bim[n], acc_re[m][n], 0, 0, 0); \
      acc_im[m][n] = __builtin_amdgcn_mfma_f32_16x16x32_bf16(ai[m],  br[n],  acc_im[m][n], 0, 0, 0); \
      acc_im[m][n] = __builtin_amdgcn_mfma_f32_16x16x32_bf16(arn[m], bim[n], acc_im[m][n], 0, 0, 0); \
    }                                                                                \
    __builtin_amdgcn_s_setprio(0);                                                   \
  } while (0)

  // ---- main loop: prefetch depth 2, counted vmcnt (never 0 until tail) ----
  STAGE(0, 0);
  STAGE(1, 1);
  int buf = 0;
  for (int s = 0; s < NT - 2; ++s) {
    int nb = buf + 2; if (nb >= 3) nb -= 3;
    STAGE(s + 2, nb);
    VMW12();                               // wait only for buffer s (12 newest stay in flight)
    __builtin_amdgcn_s_barrier();          // publish buffer s to all waves
    COMPUTE(lds + buf * LDSBUF);
    __builtin_amdgcn_s_barrier();          // protect buffer s before it is re-staged
    if (++buf == 3) buf = 0;
  }
  VMW6();
  __builtin_amdgcn_s_barrier();
  COMPUTE(lds + buf * LDSBUF);
  __builtin_amdgcn_s_barrier();
  if (++buf == 3) buf = 0;
  VMW0();
  __builtin_amdgcn_s_barrier();
  COMPUTE(lds + buf * LDSBUF);

  // ---- epilogue ----
  // C/D layout (16x16x32): col = lane&15, row = (lane>>4)*4 + reg  (verified round 1)
  const int grow0 = brow + wr * 64 + kg * 4;  // + m*16 + j
  const int gcol0 = bcol + wc * 64 + fr;      // + n*16
  const bool upperTile = (brow + BM <= bcol); // entirely strictly-upper tile

#pragma unroll
  for (int m = 0; m < 4; ++m) {
#pragma unroll
    for (int n = 0; n < 4; ++n) {
      const int gc = gcol0 + n * 16;
      f32x4 fv;
#pragma unroll
      for (int j = 0; j < 4; ++j) {
        float gr = acc_re[m][n][j];
        float gi = acc_im[m][n][j];
        fv[j] = gr * gr + gi * gi;
      }
#pragma unroll
      for (int j = 0; j < 4; ++j) {
        const int grow = grow0 + m * 16 + j;
        const float f = fv[j];
        fidp[(size_t)grow * NN + gc] = f;
        float w = 0.0f;
        if (grow < gc) w = (f >= 0.8f) ? 1.0f : ((f >= 0.5f) ? 0.5f : 0.0f);
        wts[(size_t)grow * NN + gc] = w;
      }
      if (upperTile) {  // fid symmetric: mirror 4 contiguous rows at transposed addr
        *(f32x4*)(fidp + (size_t)gc * NN + grow0 + m * 16) = fv;
      }
    }
  }

  if (upperTile) {
    // mirror region of wts (rows [bcol,bcol+256), cols [brow,brow+128)) is strictly lower -> zeros
    const f32x4 zz = {0.f, 0.f, 0.f, 0.f};
    for (int i = tid; i < 8192; i += 512) {
      const int r = i >> 5, c4 = i & 31;
      *(f32x4*)(wts + (size_t)(bcol + r) * NN + brow + c4 * 4) = zz;
    }
  }
}

extern "C" void kernel_launch(void* const* d_in, const int* in_sizes, int n_in,
                              void* d_out, int out_size, void* d_ws, size_t ws_size,
                              hipStream_t stream) {
  const float* re = (const float*)d_in[0];
  const float* im = (const float*)d_in[1];
  float* out = (float*)d_out;

  uint16_t* reb = (uint16_t*)d_ws;
  uint16_t* imb = reb + (size_t)NN * DD;

  convert_kernel<<<2048, 256, 0, stream>>>(re, im, reb, imb);
  gram_kernel<<<NTILE, 512, 0, stream>>>(reb, imb, out, out + (size_t)NN * NN);
}

// Round 3
// 1248.829 us; speedup vs baseline: 1.0588x; 1.0588x over previous
//
#include <hip/hip_runtime.h>
#include <stdint.h>

// N=8192 samples, D=4096 statevector dim (fixed by reference)
#define NN 8192
#define DD 4096
#define BM 128          // tile rows (A)
#define BN 256          // tile cols (B)
#define BK 32           // K-step
#define NT (DD / BK)    // 128 K-steps
#define LDS_A 16384     // 128 rows x 128 B (re[32]|im[32] bf16 interleaved)
#define LDS_B 32768     // 256 rows x 128 B
#define LDSBUF (LDS_A + LDS_B)   // 48 KB per buffer
#define NTILE 1056      // staircase tiles: sum_{bj=0}^{31} min(64, 2bj+2)

typedef short bf16x8 __attribute__((ext_vector_type(8)));
typedef float f32x4  __attribute__((ext_vector_type(4)));
typedef uint16_t u16x4 __attribute__((ext_vector_type(4)));

#define GLOAD(g, l) __builtin_amdgcn_global_load_lds( \
    (__attribute__((address_space(1))) uint32_t*)(void*)(size_t)(g), \
    (__attribute__((address_space(3))) uint32_t*)(void*)(l), 16, 0, 0)

#define VMW6() asm volatile("s_waitcnt vmcnt(6)" ::: "memory")
#define VMW0() asm volatile("s_waitcnt vmcnt(0)" ::: "memory")
#define LGK0() asm volatile("s_waitcnt lgkmcnt(0)" ::: "memory")

__device__ __forceinline__ uint16_t f2bf(float x) {
  uint32_t u = __builtin_bit_cast(uint32_t, x);
  return (uint16_t)((u + 0x7fffu + ((u >> 16) & 1u)) >> 16);
}

__global__ void convert_kernel(const float* __restrict__ re, const float* __restrict__ im,
                               uint16_t* __restrict__ reb, uint16_t* __restrict__ imb) {
  size_t i = (size_t)blockIdx.x * blockDim.x + threadIdx.x;
  const size_t stride = (size_t)gridDim.x * blockDim.x;
  const size_t total = (size_t)NN * DD / 4;
  for (; i < total; i += stride) {
    float4 r = ((const float4*)re)[i];
    float4 m = ((const float4*)im)[i];
    u16x4 rb = { f2bf(r.x), f2bf(r.y), f2bf(r.z), f2bf(r.w) };
    u16x4 mb = { f2bf(m.x), f2bf(m.y), f2bf(m.z), f2bf(m.w) };
    ((u16x4*)reb)[i] = rb;
    ((u16x4*)imb)[i] = mb;
  }
}

// 128x256 tile of G per block-pair (bi, bj), staircase bi < min(64, 2bj+2).
// LDS rows are 128B (re|im interleaved) with 8-slot XOR swizzle (slot ^= row&7):
// conflict-free ds_read_b128. 4 phases per K-step (16 MFMA each) with per-phase
// barriers + setprio; counted vmcnt(6); triple-buffered LDS, prefetch depth 2.
__global__ __launch_bounds__(512, 2) void gram_kernel(
    const uint16_t* __restrict__ reb, const uint16_t* __restrict__ imb,
    float* __restrict__ wts, float* __restrict__ fidp) {
  __shared__ alignas(16) char lds[3 * LDSBUF];  // 144 KB

  // XCD-aware bijective swizzle (1056 = 8*132)
  const int b = blockIdx.x;
  int t = (b & 7) * 132 + (b >> 3);

  int bi = 0, bj = 0;
  {
    int acc = 0;
    for (int j = 0; j < 32; ++j) {
      int cnt = 2 * j + 2; if (cnt > 64) cnt = 64;
      if (t < acc + cnt) { bj = j; bi = t - acc; break; }
      acc += cnt;
    }
  }
  const int brow = bi * BM, bcol = bj * BN;

  const int tid = threadIdx.x;
  const int lane = tid & 63;
  const int wid = tid >> 6;               // 8 waves
  const int wr = wid >> 2, wc = wid & 3;  // 2x4 wave grid, 64x64 out per wave
  const int t16 = tid * 16;

  // ---- staging source (pre-swizzled; LDS dest stays linear = tid*16) ----
  // LDS tile row r (128 B): physical slot p holds logical slot p ^ (r&7);
  // logical slots 0-3 = re chunks, 4-7 = im chunks.
  const int srow = tid >> 3;                    // 0..63
  const int slog = (tid & 7) ^ (srow & 7);
  const uint16_t* smat = (slog < 4) ? reb : imb;
  const int scol = (slog & 3) * 8;
  const uint16_t* spA = smat + (size_t)(brow + srow) * DD + scol;
  const uint16_t* spB = smat + (size_t)(bcol + srow) * DD + scol;
  const size_t r64 = (size_t)64 * DD;

#define STAGE_A(s, bf) do { const size_t ko = (size_t)(s) * BK;            \
    char* lb_ = lds + (bf) * LDSBUF + t16;                                 \
    GLOAD(spA + ko, lb_); GLOAD(spA + ko + r64, lb_ + 8192); } while (0)
#define STAGE_B01(s, bf) do { const size_t ko = (size_t)(s) * BK;          \
    char* lb_ = lds + (bf) * LDSBUF + LDS_A + t16;                         \
    GLOAD(spB + ko, lb_); GLOAD(spB + ko + r64, lb_ + 8192); } while (0)
#define STAGE_B23(s, bf) do { const size_t ko = (size_t)(s) * BK;          \
    char* lb_ = lds + (bf) * LDSBUF + LDS_A + t16;                         \
    GLOAD(spB + ko + 2 * r64, lb_ + 16384);                                \
    GLOAD(spB + ko + 3 * r64, lb_ + 24576); } while (0)

  // ---- fragment read offsets (swizzled: slot_phys = kg ^ (row&7), row&7 = fr&7) ----
  const int fr = lane & 15;
  const int kg = lane >> 4;
  const int reslot = (kg ^ (fr & 7)) << 4;   // re frag byte slot; im = reslot^64
  const int arow = (wr * 64 + fr) * 128;     // + m*2048
  const int brw  = (wc * 64 + fr) * 128;     // + n*2048

  f32x4 acc_re[4][4], acc_im[4][4];
  const f32x4 z4 = {0.f, 0.f, 0.f, 0.f};
#pragma unroll
  for (int m = 0; m < 4; ++m)
#pragma unroll
    for (int n = 0; n < 4; ++n) { acc_re[m][n] = z4; acc_im[m][n] = z4; }

#define MFMA16(n) do {                                                               \
    _Pragma("unroll") for (int m = 0; m < 4; ++m) {                                  \
      acc_re[m][n] = __builtin_amdgcn_mfma_f32_16x16x32_bf16(ar[m],  br,  acc_re[m][n], 0, 0, 0); \
      acc_re[m][n] = __builtin_amdgcn_mfma_f32_16x16x32_bf16(ai[m],  bim, acc_re[m][n], 0, 0, 0); \
      acc_im[m][n] = __builtin_amdgcn_mfma_f32_16x16x32_bf16(ai[m],  br,  acc_im[m][n], 0, 0, 0); \
      acc_im[m][n] = __builtin_amdgcn_mfma_f32_16x16x32_bf16(arn[m], bim, acc_im[m][n], 0, 0, 0); \
    } } while (0)

  // ---- prologue: stage buffers 0,1; publish buffer 0 ----
  STAGE_A(0, 0); STAGE_B01(0, 0); STAGE_B23(0, 0);
  STAGE_A(1, 1); STAGE_B01(1, 1); STAGE_B23(1, 1);
  VMW6();
  __builtin_amdgcn_s_barrier();

  int buf = 0;
  for (int s = 0; s < NT; ++s) {
    const char* la  = lds + buf * LDSBUF;
    const char* lbt = la + LDS_A;
    int nb = buf + 2; if (nb >= 3) nb -= 3;
    bf16x8 ar[4], ai[4], arn[4], br, bim;

    // ---- phase 0: A frags + B0 ; stage A(s+2) ----
#pragma unroll
    for (int m = 0; m < 4; ++m) {
      ar[m]  = *(const bf16x8*)(la + arow + m * 2048 + reslot);
      ai[m]  = *(const bf16x8*)(la + arow + m * 2048 + (reslot ^ 64));
      arn[m] = ar[m] ^ (short)0x8000;
    }
    br  = *(const bf16x8*)(lbt + brw + 0 * 2048 + reslot);
    bim = *(const bf16x8*)(lbt + brw + 0 * 2048 + (reslot ^ 64));
    if (s + 2 < NT) STAGE_A(s + 2, nb);
    __builtin_amdgcn_s_barrier();
    LGK0(); __builtin_amdgcn_sched_barrier(0);
    __builtin_amdgcn_s_setprio(1);
    MFMA16(0);
    __builtin_amdgcn_s_setprio(0);
    __builtin_amdgcn_s_barrier();

    // ---- phase 1: B1 ; stage B01(s+2) ----
    br  = *(const bf16x8*)(lbt + brw + 1 * 2048 + reslot);
    bim = *(const bf16x8*)(lbt + brw + 1 * 2048 + (reslot ^ 64));
    if (s + 2 < NT) STAGE_B01(s + 2, nb);
    __builtin_amdgcn_s_barrier();
    LGK0(); __builtin_amdgcn_sched_barrier(0);
    __builtin_amdgcn_s_setprio(1);
    MFMA16(1);
    __builtin_amdgcn_s_setprio(0);
    __builtin_amdgcn_s_barrier();

    // ---- phase 2: B2 ; stage B23(s+2) ----
    br  = *(const bf16x8*)(lbt + brw + 2 * 2048 + reslot);
    bim = *(const bf16x8*)(lbt + brw + 2 * 2048 + (reslot ^ 64));
    if (s + 2 < NT) STAGE_B23(s + 2, nb);
    __builtin_amdgcn_s_barrier();
    LGK0(); __builtin_amdgcn_sched_barrier(0);
    __builtin_amdgcn_s_setprio(1);
    MFMA16(2);
    __builtin_amdgcn_s_setprio(0);
    __builtin_amdgcn_s_barrier();

    // ---- phase 3: B3 ; counted vmcnt for next step's buffer ----
    br  = *(const bf16x8*)(lbt + brw + 3 * 2048 + reslot);
    bim = *(const bf16x8*)(lbt + brw + 3 * 2048 + (reslot ^ 64));
    if (s + 2 < NT) { VMW6(); } else { VMW0(); }
    __builtin_amdgcn_s_barrier();
    LGK0(); __builtin_amdgcn_sched_barrier(0);
    __builtin_amdgcn_s_setprio(1);
    MFMA16(3);
    __builtin_amdgcn_s_setprio(0);
    __builtin_amdgcn_s_barrier();

    if (++buf == 3) buf = 0;
  }

  // ---- epilogue (verified rounds 1-2) ----
  // C/D layout (16x16x32): col = lane&15, row = (lane>>4)*4 + reg
  const int grow0 = brow + wr * 64 + kg * 4;  // + m*16 + j
  const int gcol0 = bcol + wc * 64 + fr;      // + n*16
  const bool upperTile = (brow + BM <= bcol);

#pragma unroll
  for (int m = 0; m < 4; ++m) {
#pragma unroll
    for (int n = 0; n < 4; ++n) {
      const int gc = gcol0 + n * 16;
      f32x4 fv;
#pragma unroll
      for (int j = 0; j < 4; ++j) {
        float gr = acc_re[m][n][j];
        float gi = acc_im[m][n][j];
        fv[j] = gr * gr + gi * gi;
      }
#pragma unroll
      for (int j = 0; j < 4; ++j) {
        const int grow = grow0 + m * 16 + j;
        const float f = fv[j];
        fidp[(size_t)grow * NN + gc] = f;
        float w = 0.0f;
        if (grow < gc) w = (f >= 0.8f) ? 1.0f : ((f >= 0.5f) ? 0.5f : 0.0f);
        wts[(size_t)grow * NN + gc] = w;
      }
      if (upperTile) {  // fid symmetric: mirror 4 contiguous rows at transposed addr
        *(f32x4*)(fidp + (size_t)gc * NN + grow0 + m * 16) = fv;
      }
    }
  }

  if (upperTile) {
    // mirror region of wts (rows [bcol,bcol+256), cols [brow,brow+128)) strictly lower -> zeros
    const f32x4 zz = {0.f, 0.f, 0.f, 0.f};
    for (int i = tid; i < 8192; i += 512) {
      const int r = i >> 5, c4 = i & 31;
      *(f32x4*)(wts + (size_t)(bcol + r) * NN + brow + c4 * 4) = zz;
    }
  }
}

extern "C" void kernel_launch(void* const* d_in, const int* in_sizes, int n_in,
                              void* d_out, int out_size, void* d_ws, size_t ws_size,
                              hipStream_t stream) {
  const float* re = (const float*)d_in[0];
  const float* im = (const float*)d_in[1];
  float* out = (float*)d_out;

  uint16_t* reb = (uint16_t*)d_ws;
  uint16_t* imb = reb + (size_t)NN * DD;

  convert_kernel<<<2048, 256, 0, stream>>>(re, im, reb, imb);
  gram_kernel<<<NTILE, 512, 0, stream>>>(reb, imb, out, out + (size_t)NN * NN);
}

// Round 4
// 1138.434 us; speedup vs baseline: 1.1615x; 1.0970x over previous
//
#include <hip/hip_runtime.h>
#include <stdint.h>

// N=8192 samples, D=4096 statevector dim (fixed by reference)
#define NN 8192
#define DD 4096
#define BK 32           // K-step
#define NT (DD / BK)    // 128 K-steps
#define NBLK 64         // 8192 / 128
#define LDS_T 16384     // one tile: 128 rows x 128 B (re[32]|im[32] bf16, 8-slot XOR swizzle)
#define LDSBUF 32768    // A tile + B tile
#define NTILE 2080      // upper-tri incl diagonal: 64*65/2

typedef short bf16x8 __attribute__((ext_vector_type(8)));
typedef float f32x4  __attribute__((ext_vector_type(4)));
typedef uint16_t u16x4 __attribute__((ext_vector_type(4)));

#define GLOAD(g, l) __builtin_amdgcn_global_load_lds( \
    (__attribute__((address_space(1))) uint32_t*)(void*)(size_t)(g), \
    (__attribute__((address_space(3))) uint32_t*)(void*)(l), 16, 0, 0)

#define VMW0() asm volatile("s_waitcnt vmcnt(0)" ::: "memory")
#define LGK0() asm volatile("s_waitcnt lgkmcnt(0)" ::: "memory")

__device__ __forceinline__ uint16_t f2bf(float x) {
  uint32_t u = __builtin_bit_cast(uint32_t, x);
  return (uint16_t)((u + 0x7fffu + ((u >> 16) & 1u)) >> 16);
}

__global__ void convert_kernel(const float* __restrict__ re, const float* __restrict__ im,
                               uint16_t* __restrict__ reb, uint16_t* __restrict__ imb) {
  size_t i = (size_t)blockIdx.x * blockDim.x + threadIdx.x;
  const size_t stride = (size_t)gridDim.x * blockDim.x;
  const size_t total = (size_t)NN * DD / 4;
  for (; i < total; i += stride) {
    float4 r = ((const float4*)re)[i];
    float4 m = ((const float4*)im)[i];
    u16x4 rb = { f2bf(r.x), f2bf(r.y), f2bf(r.z), f2bf(r.w) };
    u16x4 mb = { f2bf(m.x), f2bf(m.y), f2bf(m.z), f2bf(m.w) };
    ((u16x4*)reb)[i] = rb;
    ((u16x4*)imb)[i] = mb;
  }
}

// 128x128 tile of G per block-pair (bi, bj), bi <= bj. 4 waves (64x64 out each),
// double-buffered 64 KB LDS -> 2 blocks/CU (cross-block overlap fills phase bubbles).
// Conflict-free XOR-swizzled LDS (verified: SQ_LDS_BANK_CONFLICT == 0), 4 phases of
// 16 MFMA per K-step with per-phase barriers + setprio; staging in P0/P1, vmcnt(0)
// only at end of P3 (~600 cy slack).
__global__ __launch_bounds__(256, 2) void gram_kernel(
    const uint16_t* __restrict__ reb, const uint16_t* __restrict__ imb,
    float* __restrict__ wts, float* __restrict__ fidp) {
  __shared__ alignas(16) char lds[2 * LDSBUF];  // 64 KB

  // XCD-aware bijective swizzle (2080 = 8*260)
  const int b = blockIdx.x;
  const int t = (b & 7) * 260 + (b >> 3);

  // t -> (bi, bj), bi <= bj (verified round 1)
  int bi = (int)(((float)(2 * NBLK + 1) -
                  sqrtf((float)((2 * NBLK + 1) * (2 * NBLK + 1) - 8 * t))) * 0.5f);
  if (bi < 0) bi = 0;
  if (bi > NBLK - 1) bi = NBLK - 1;
  while (bi > 0 && t < bi * NBLK - bi * (bi - 1) / 2) --bi;
  while (t >= (bi + 1) * NBLK - (bi + 1) * bi / 2) ++bi;
  const int bj = bi + (t - (bi * NBLK - bi * (bi - 1) / 2));

  const int brow = bi * 128, bcol = bj * 128;
  const int tid = threadIdx.x;
  const int lane = tid & 63;
  const int wid = tid >> 6;               // 4 waves
  const int wr = wid >> 1, wc = wid & 1;  // 2x2 wave grid, 64x64 out per wave
  const int t16 = tid * 16;

  // ---- staging source (pre-swizzled; LDS dest linear = round*4096 + tid*16) ----
  // LDS row r (128 B): physical slot p holds logical slot p ^ (r&7);
  // logical slots 0-3 = re chunks, 4-7 = im chunks.
  const int srow = tid >> 3;                     // 0..31 (rounds add 32)
  const int slog = (tid & 7) ^ (srow & 7);       // 32 ≡ 0 mod 8 -> constant across rounds
  const uint16_t* smat = (slog < 4) ? reb : imb;
  const int scol = (slog & 3) * 8;
  const uint16_t* spA = smat + (size_t)(brow + srow) * DD + scol;
  const uint16_t* spB = smat + (size_t)(bcol + srow) * DD + scol;
  const size_t r32 = (size_t)32 * DD;

#define STAGE_A(s, bf) do { const size_t ko = (size_t)(s) * BK;                 \
    char* lb_ = lds + (bf) * LDSBUF + t16;                                      \
    GLOAD(spA + ko,           lb_);                                             \
    GLOAD(spA + ko + r32,     lb_ + 4096);                                      \
    GLOAD(spA + ko + 2 * r32, lb_ + 8192);                                      \
    GLOAD(spA + ko + 3 * r32, lb_ + 12288); } while (0)
#define STAGE_B(s, bf) do { const size_t ko = (size_t)(s) * BK;                 \
    char* lb_ = lds + (bf) * LDSBUF + LDS_T + t16;                              \
    GLOAD(spB + ko,           lb_);                                             \
    GLOAD(spB + ko + r32,     lb_ + 4096);                                      \
    GLOAD(spB + ko + 2 * r32, lb_ + 8192);                                      \
    GLOAD(spB + ko + 3 * r32, lb_ + 12288); } while (0)

  // ---- fragment read offsets (slot_phys = kg ^ (row&7), row&7 = fr&7) ----
  const int fr = lane & 15;
  const int kg = lane >> 4;
  const int reslot = (kg ^ (fr & 7)) << 4;   // re frag byte slot; im = reslot^64
  const int arow = (wr * 64 + fr) * 128;     // + m*2048
  const int brw  = (wc * 64 + fr) * 128;     // + n*2048

  f32x4 acc_re[4][4], acc_im[4][4];
  const f32x4 z4 = {0.f, 0.f, 0.f, 0.f};
#pragma unroll
  for (int m = 0; m < 4; ++m)
#pragma unroll
    for (int n = 0; n < 4; ++n) { acc_re[m][n] = z4; acc_im[m][n] = z4; }

#define MFMA16(n) do {                                                               \
    _Pragma("unroll") for (int m = 0; m < 4; ++m) {                                  \
      acc_re[m][n] = __builtin_amdgcn_mfma_f32_16x16x32_bf16(ar[m],  br,  acc_re[m][n], 0, 0, 0); \
      acc_re[m][n] = __builtin_amdgcn_mfma_f32_16x16x32_bf16(ai[m],  bim, acc_re[m][n], 0, 0, 0); \
      acc_im[m][n] = __builtin_amdgcn_mfma_f32_16x16x32_bf16(ai[m],  br,  acc_im[m][n], 0, 0, 0); \
      acc_im[m][n] = __builtin_amdgcn_mfma_f32_16x16x32_bf16(arn[m], bim, acc_im[m][n], 0, 0, 0); \
    } } while (0)

  // ---- prologue ----
  STAGE_A(0, 0); STAGE_B(0, 0);
  VMW0();
  __builtin_amdgcn_s_barrier();

  for (int s = 0; s < NT; ++s) {
    const char* la  = lds + (s & 1) * LDSBUF;
    const char* lbt = la + LDS_T;
    const int nb = (s & 1) ^ 1;
    bf16x8 ar[4], ai[4], arn[4], br, bim;

    // ---- phase 0: A frags + B0 ; stage A(s+1) ----
#pragma unroll
    for (int m = 0; m < 4; ++m) {
      ar[m]  = *(const bf16x8*)(la + arow + m * 2048 + reslot);
      ai[m]  = *(const bf16x8*)(la + arow + m * 2048 + (reslot ^ 64));
      arn[m] = ar[m] ^ (short)0x8000;
    }
    br  = *(const bf16x8*)(lbt + brw + 0 * 2048 + reslot);
    bim = *(const bf16x8*)(lbt + brw + 0 * 2048 + (reslot ^ 64));
    if (s + 1 < NT) STAGE_A(s + 1, nb);
    __builtin_amdgcn_s_barrier();
    LGK0(); __builtin_amdgcn_sched_barrier(0);
    __builtin_amdgcn_s_setprio(1);
    MFMA16(0);
    __builtin_amdgcn_s_setprio(0);
    __builtin_amdgcn_s_barrier();

    // ---- phase 1: B1 ; stage B(s+1) ----
    br  = *(const bf16x8*)(lbt + brw + 1 * 2048 + reslot);
    bim = *(const bf16x8*)(lbt + brw + 1 * 2048 + (reslot ^ 64));
    if (s + 1 < NT) STAGE_B(s + 1, nb);
    __builtin_amdgcn_s_barrier();
    LGK0(); __builtin_amdgcn_sched_barrier(0);
    __builtin_amdgcn_s_setprio(1);
    MFMA16(1);
    __builtin_amdgcn_s_setprio(0);
    __builtin_amdgcn_s_barrier();

    // ---- phase 2: B2 ----
    br  = *(const bf16x8*)(lbt + brw + 2 * 2048 + reslot);
    bim = *(const bf16x8*)(lbt + brw + 2 * 2048 + (reslot ^ 64));
    __builtin_amdgcn_s_barrier();
    LGK0(); __builtin_amdgcn_sched_barrier(0);
    __builtin_amdgcn_s_setprio(1);
    MFMA16(2);
    __builtin_amdgcn_s_setprio(0);
    __builtin_amdgcn_s_barrier();

    // ---- phase 3: B3 ; drain stage before buffer flip ----
    br  = *(const bf16x8*)(lbt + brw + 3 * 2048 + reslot);
    bim = *(const bf16x8*)(lbt + brw + 3 * 2048 + (reslot ^ 64));
    VMW0();
    __builtin_amdgcn_s_barrier();
    LGK0(); __builtin_amdgcn_sched_barrier(0);
    __builtin_amdgcn_s_setprio(1);
    MFMA16(3);
    __builtin_amdgcn_s_setprio(0);
    __builtin_amdgcn_s_barrier();
  }

  // ---- epilogue (verified rounds 1-3) ----
  // C/D layout (16x16x32): col = lane&15, row = (lane>>4)*4 + reg
  const int grow0 = brow + wr * 64 + kg * 4;  // + m*16 + j
  const int gcol0 = bcol + wc * 64 + fr;      // + n*16

#pragma unroll
  for (int m = 0; m < 4; ++m) {
#pragma unroll
    for (int n = 0; n < 4; ++n) {
      const int gc = gcol0 + n * 16;
      f32x4 fv;
#pragma unroll
      for (int j = 0; j < 4; ++j) {
        float gr = acc_re[m][n][j];
        float gi = acc_im[m][n][j];
        fv[j] = gr * gr + gi * gi;
      }
#pragma unroll
      for (int j = 0; j < 4; ++j) {
        const int grow = grow0 + m * 16 + j;
        const float f = fv[j];
        fidp[(size_t)grow * NN + gc] = f;
        float w = 0.0f;
        if (grow < gc) w = (f >= 0.8f) ? 1.0f : ((f >= 0.5f) ? 0.5f : 0.0f);
        wts[(size_t)grow * NN + gc] = w;
      }
      if (bi != bj) {  // fid symmetric: mirror 4 contiguous rows at transposed addr
        *(f32x4*)(fidp + (size_t)gc * NN + grow0 + m * 16) = fv;
      }
    }
  }

  if (bi != bj) {
    // mirror block (bj,bi) of wts is strictly lower-triangular -> zeros
    const f32x4 zz = {0.f, 0.f, 0.f, 0.f};
    for (int i = tid; i < 4096; i += 256) {
      const int r = i >> 5, c4 = i & 31;
      *(f32x4*)(wts + (size_t)(bcol + r) * NN + brow + c4 * 4) = zz;
    }
  }
}

extern "C" void kernel_launch(void* const* d_in, const int* in_sizes, int n_in,
                              void* d_out, int out_size, void* d_ws, size_t ws_size,
                              hipStream_t stream) {
  const float* re = (const float*)d_in[0];
  const float* im = (const float*)d_in[1];
  float* out = (float*)d_out;

  uint16_t* reb = (uint16_t*)d_ws;
  uint16_t* imb = reb + (size_t)NN * DD;

  convert_kernel<<<2048, 256, 0, stream>>>(re, im, reb, imb);
  gram_kernel<<<NTILE, 256, 0, stream>>>(reb, imb, out, out + (size_t)NN * NN);
}

// Round 5
// 1098.483 us; speedup vs baseline: 1.2038x; 1.0364x over previous
//
#include <hip/hip_runtime.h>
#include <stdint.h>

// N=8192 samples, D=4096 statevector dim (fixed by reference)
#define NN 8192
#define DD 4096
#define BK 32           // K-step
#define NT (DD / BK)    // 128 K-steps
#define NBLK 64         // 8192 / 128
#define LDS_T 16384     // one tile: 128 rows x 128 B (re[32]|im[32] bf16, 8-slot XOR swizzle)
#define LDSBUF 32768    // A tile + B tile
#define NTILE 2080      // upper-tri incl diagonal: 64*65/2

typedef short bf16x8 __attribute__((ext_vector_type(8)));
typedef float f32x4  __attribute__((ext_vector_type(4)));
typedef uint16_t u16x4 __attribute__((ext_vector_type(4)));

#define GLOAD(g, l) __builtin_amdgcn_global_load_lds( \
    (__attribute__((address_space(1))) uint32_t*)(void*)(size_t)(g), \
    (__attribute__((address_space(3))) uint32_t*)(void*)(l), 16, 0, 0)

#define VMW0() asm volatile("s_waitcnt vmcnt(0)" ::: "memory")
#define LGK0() asm volatile("s_waitcnt lgkmcnt(0)" ::: "memory")

__device__ __forceinline__ uint16_t f2bf(float x) {
  uint32_t u = __builtin_bit_cast(uint32_t, x);
  return (uint16_t)((u + 0x7fffu + ((u >> 16) & 1u)) >> 16);
}

__global__ void convert_kernel(const float* __restrict__ re, const float* __restrict__ im,
                               uint16_t* __restrict__ reb, uint16_t* __restrict__ imb) {
  size_t i = (size_t)blockIdx.x * blockDim.x + threadIdx.x;
  const size_t stride = (size_t)gridDim.x * blockDim.x;
  const size_t total = (size_t)NN * DD / 4;
  for (; i < total; i += stride) {
    float4 r = ((const float4*)re)[i];
    float4 m = ((const float4*)im)[i];
    u16x4 rb = { f2bf(r.x), f2bf(r.y), f2bf(r.z), f2bf(r.w) };
    u16x4 mb = { f2bf(m.x), f2bf(m.y), f2bf(m.z), f2bf(m.w) };
    ((u16x4*)reb)[i] = rb;
    ((u16x4*)imb)[i] = mb;
  }
}

// 128x128 tile of G per block-pair (bi, bj), bi <= bj. 4 waves (64x64 out each),
// double-buffered 64 KB LDS -> 2 blocks/CU. Conflict-free XOR-swizzled LDS (verified
// SQ_LDS_BANK_CONFLICT == 0). Round-5 schedule: register-pipelined B-fragments,
// ONE barrier per K-step (reads consumed before barrier; staging drained by vmcnt(0)),
// GLOADs for step s+1 issued at top of step s (in flight ~whole step).
__global__ __launch_bounds__(256, 2) void gram_kernel(
    const uint16_t* __restrict__ reb, const uint16_t* __restrict__ imb,
    float* __restrict__ wts, float* __restrict__ fidp) {
  __shared__ alignas(16) char lds[2 * LDSBUF];  // 64 KB

  // XCD-aware bijective swizzle (2080 = 8*260)
  const int b = blockIdx.x;
  const int t = (b & 7) * 260 + (b >> 3);

  // t -> (bi, bj), bi <= bj (verified round 1)
  int bi = (int)(((float)(2 * NBLK + 1) -
                  sqrtf((float)((2 * NBLK + 1) * (2 * NBLK + 1) - 8 * t))) * 0.5f);
  if (bi < 0) bi = 0;
  if (bi > NBLK - 1) bi = NBLK - 1;
  while (bi > 0 && t < bi * NBLK - bi * (bi - 1) / 2) --bi;
  while (t >= (bi + 1) * NBLK - (bi + 1) * bi / 2) ++bi;
  const int bj = bi + (t - (bi * NBLK - bi * (bi - 1) / 2));

  const int brow = bi * 128, bcol = bj * 128;
  const int tid = threadIdx.x;
  const int lane = tid & 63;
  const int wid = tid >> 6;               // 4 waves
  const int wr = wid >> 1, wc = wid & 1;  // 2x2 wave grid, 64x64 out per wave
  const int t16 = tid * 16;

  // ---- staging source (pre-swizzled; LDS dest linear = round*4096 + tid*16) ----
  // LDS row r (128 B): physical slot p holds logical slot p ^ (r&7);
  // logical slots 0-3 = re chunks, 4-7 = im chunks.
  const int srow = tid >> 3;                     // 0..31 (rounds add 32)
  const int slog = (tid & 7) ^ (srow & 7);       // 32 ≡ 0 mod 8 -> constant across rounds
  const uint16_t* smat = (slog < 4) ? reb : imb;
  const int scol = (slog & 3) * 8;
  const uint16_t* spA = smat + (size_t)(brow + srow) * DD + scol;
  const uint16_t* spB = smat + (size_t)(bcol + srow) * DD + scol;
  const size_t r32 = (size_t)32 * DD;

#define STAGE_A(s, bf) do { const size_t ko = (size_t)(s) * BK;                 \
    char* lb_ = lds + (bf) * LDSBUF + t16;                                      \
    GLOAD(spA + ko,           lb_);                                             \
    GLOAD(spA + ko + r32,     lb_ + 4096);                                      \
    GLOAD(spA + ko + 2 * r32, lb_ + 8192);                                      \
    GLOAD(spA + ko + 3 * r32, lb_ + 12288); } while (0)
#define STAGE_B(s, bf) do { const size_t ko = (size_t)(s) * BK;                 \
    char* lb_ = lds + (bf) * LDSBUF + LDS_T + t16;                              \
    GLOAD(spB + ko,           lb_);                                             \
    GLOAD(spB + ko + r32,     lb_ + 4096);                                      \
    GLOAD(spB + ko + 2 * r32, lb_ + 8192);                                      \
    GLOAD(spB + ko + 3 * r32, lb_ + 12288); } while (0)

  // ---- fragment read offsets (slot_phys = kg ^ (row&7), row&7 = fr&7) ----
  const int fr = lane & 15;
  const int kg = lane >> 4;
  const int reslot = (kg ^ (fr & 7)) << 4;   // re frag byte slot; im = reslot^64
  const int arow = (wr * 64 + fr) * 128;     // + m*2048
  const int brw  = (wc * 64 + fr) * 128;     // + n*2048

  f32x4 acc_re[4][4], acc_im[4][4];
  const f32x4 z4 = {0.f, 0.f, 0.f, 0.f};
#pragma unroll
  for (int m = 0; m < 4; ++m)
#pragma unroll
    for (int n = 0; n < 4; ++n) { acc_re[m][n] = z4; acc_im[m][n] = z4; }

#define MFMA16(n, brv, biv) do {                                                     \
    _Pragma("unroll") for (int m = 0; m < 4; ++m) {                                  \
      acc_re[m][n] = __builtin_amdgcn_mfma_f32_16x16x32_bf16(ar[m],  brv, acc_re[m][n], 0, 0, 0); \
      acc_re[m][n] = __builtin_amdgcn_mfma_f32_16x16x32_bf16(ai[m],  biv, acc_re[m][n], 0, 0, 0); \
      acc_im[m][n] = __builtin_amdgcn_mfma_f32_16x16x32_bf16(ai[m],  brv, acc_im[m][n], 0, 0, 0); \
      acc_im[m][n] = __builtin_amdgcn_mfma_f32_16x16x32_bf16(arn[m], biv, acc_im[m][n], 0, 0, 0); \
    } } while (0)

  // ---- prologue ----
  STAGE_A(0, 0); STAGE_B(0, 0);
  VMW0();
  __builtin_amdgcn_s_barrier();

  for (int s = 0; s < NT; ++s) {
    const char* la  = lds + (s & 1) * LDSBUF;
    const char* lbt = la + LDS_T;
    const int nb = (s & 1) ^ 1;

    // stage next K-step first: GLOADs in flight for the whole step (~1200 cy)
    if (s + 1 < NT) { STAGE_A(s + 1, nb); STAGE_B(s + 1, nb); }

    // A fragments + B0; B(p+1) issued before MFMA(p) -> compiler emits counted lgkmcnt
    bf16x8 ar[4], ai[4], arn[4];
#pragma unroll
    for (int m = 0; m < 4; ++m) {
      ar[m] = *(const bf16x8*)(la + arow + m * 2048 + reslot);
      ai[m] = *(const bf16x8*)(la + arow + m * 2048 + (reslot ^ 64));
    }
    bf16x8 br0 = *(const bf16x8*)(lbt + brw + 0 * 2048 + reslot);
    bf16x8 bi0 = *(const bf16x8*)(lbt + brw + 0 * 2048 + (reslot ^ 64));
    bf16x8 br1 = *(const bf16x8*)(lbt + brw + 1 * 2048 + reslot);
    bf16x8 bi1 = *(const bf16x8*)(lbt + brw + 1 * 2048 + (reslot ^ 64));
#pragma unroll
    for (int m = 0; m < 4; ++m) arn[m] = ar[m] ^ (short)0x8000;

    __builtin_amdgcn_s_setprio(1);
    MFMA16(0, br0, bi0);
    __builtin_amdgcn_s_setprio(0);
    bf16x8 br2 = *(const bf16x8*)(lbt + brw + 2 * 2048 + reslot);
    bf16x8 bi2 = *(const bf16x8*)(lbt + brw + 2 * 2048 + (reslot ^ 64));
    __builtin_amdgcn_s_setprio(1);
    MFMA16(1, br1, bi1);
    __builtin_amdgcn_s_setprio(0);
    bf16x8 br3 = *(const bf16x8*)(lbt + brw + 3 * 2048 + reslot);
    bf16x8 bi3 = *(const bf16x8*)(lbt + brw + 3 * 2048 + (reslot ^ 64));
    __builtin_amdgcn_s_setprio(1);
    MFMA16(2, br2, bi2);
    MFMA16(3, br3, bi3);
    __builtin_amdgcn_s_setprio(0);

    // all reads of buf[cur] consumed; staging for s+1 drained; ONE barrier per step
    LGK0();
    VMW0();
    __builtin_amdgcn_s_barrier();
  }

  // ---- epilogue (verified rounds 1-4) ----
  // C/D layout (16x16x32): col = lane&15, row = (lane>>4)*4 + reg
  const int grow0 = brow + wr * 64 + kg * 4;  // + m*16 + j
  const int gcol0 = bcol + wc * 64 + fr;      // + n*16

#pragma unroll
  for (int m = 0; m < 4; ++m) {
#pragma unroll
    for (int n = 0; n < 4; ++n) {
      const int gc = gcol0 + n * 16;
      f32x4 fv;
#pragma unroll
      for (int j = 0; j < 4; ++j) {
        float gr = acc_re[m][n][j];
        float gi = acc_im[m][n][j];
        fv[j] = gr * gr + gi * gi;
      }
#pragma unroll
      for (int j = 0; j < 4; ++j) {
        const int grow = grow0 + m * 16 + j;
        const float f = fv[j];
        fidp[(size_t)grow * NN + gc] = f;
        float w = 0.0f;
        if (grow < gc) w = (f >= 0.8f) ? 1.0f : ((f >= 0.5f) ? 0.5f : 0.0f);
        wts[(size_t)grow * NN + gc] = w;
      }
      if (bi != bj) {  // fid symmetric: mirror 4 contiguous rows at transposed addr
        *(f32x4*)(fidp + (size_t)gc * NN + grow0 + m * 16) = fv;
      }
    }
  }

  if (bi != bj) {
    // mirror block (bj,bi) of wts is strictly lower-triangular -> zeros
    const f32x4 zz = {0.f, 0.f, 0.f, 0.f};
    for (int i = tid; i < 4096; i += 256) {
      const int r = i >> 5, c4 = i & 31;
      *(f32x4*)(wts + (size_t)(bcol + r) * NN + brow + c4 * 4) = zz;
    }
  }
}

extern "C" void kernel_launch(void* const* d_in, const int* in_sizes, int n_in,
                              void* d_out, int out_size, void* d_ws, size_t ws_size,
                              hipStream_t stream) {
  const float* re = (const float*)d_in[0];
  const float* im = (const float*)d_in[1];
  float* out = (float*)d_out;

  uint16_t* reb = (uint16_t*)d_ws;
  uint16_t* imb = reb + (size_t)NN * DD;

  convert_kernel<<<2048, 256, 0, stream>>>(re, im, reb, imb);
  gram_kernel<<<NTILE, 256, 0, stream>>>(reb, imb, out, out + (size_t)NN * NN);
}